// Round 1
// baseline (111.163 us; speedup 1.0000x reference)
//
#include <hip/hip_runtime.h>

// FDN reverb == 8-tap sparse FIR + 50/50 mix + global max-abs normalize.
// R5 restructure, two levers vs the 107us version:
//  1) ALL tap reads are now aligned ds_read_b128 (pairs for misaligned
//     delays, compile-time register select). The old scalar/b64 odd-tap
//     reads at 16B lane stride hit 8 banks x 8 lanes = 8-way conflict
//     (~2.94x per m136); consecutive-b128 is the conflict-free pattern.
//  2) Pass A stores the un-normalized output (regular stores -> L2
//     write-allocate) instead of pass B recomputing the whole FIR.
//     Pass B is now a trivial elementwise scale: read (mostly L2-hit,
//     same physical block -> same XCD as the pass-A writer) + one
//     nontemporal write. Trades ~5-8us of traffic for ~35us of
//     recomputed conflicted-LDS FIR.
// Block swizzle unchanged: each XCD owns a contiguous 4MB region of x.
#define T_LEN 8388608
#define CHUNK 4096               // outputs per block
#define HALO  3840               // >= max delay (3825), multiple of 4
#define LDSF  (HALO + CHUNK)     // 7936 floats = 31744 B -> 5 blocks/CU
#define NBLK  (T_LEN / CHUNK)    // 2048 blocks

#define D0 1425   // %4 == 1
#define D1 1780   // %4 == 0
#define D2 1972   // %4 == 0
#define D3 2097   // %4 == 1
#define D4 2558   // %4 == 2
#define D5 2961   // %4 == 1
#define D6 3508   // %4 == 0
#define D7 3825   // %4 == 1

typedef float floatx4 __attribute__((ext_vector_type(4)));  // nontemporal store

__device__ __forceinline__ int swz(int b) {
    // phys block -> logical chunk: XCD k (b%8) owns contiguous [k*256,(k+1)*256)
    return (b & 7) * (NBLK / 8) + (b >> 3);
}

// Read 4 consecutive floats at p - D from LDS using only aligned b128s.
// r = misalignment phase (compile-time); q = 16B-aligned base below p-D.
// Lane stride is 16B and addresses are consecutive across lanes ->
// conflict-free. Select of w[r..r+3] is fully static -> registers only.
template <int D>
__device__ __forceinline__ void tap4(const float* __restrict__ p, float v[4]) {
    constexpr int r = (4 - (D & 3)) & 3;
    const float* q = p - D - r;              // 16B-aligned (p is 0 mod 4)
    float4 w0 = *(const float4*)q;
    if constexpr (r == 0) {
        v[0] = w0.x; v[1] = w0.y; v[2] = w0.z; v[3] = w0.w;
    } else {
        float4 w1 = *(const float4*)(q + 4);
        float w[8] = {w0.x, w0.y, w0.z, w0.w, w1.x, w1.y, w1.z, w1.w};
#pragma unroll
        for (int k = 0; k < 4; ++k) v[k] = w[r + k];  // r+k compile-time
    }
}

// Compute 4 outputs at LDS pointer p (16B-aligned), coefficients c[8].
__device__ __forceinline__ float4 quad_fir(const float* __restrict__ p,
                                           const float* __restrict__ c) {
    float4 dry = *(const float4*)(p);
    float t0v[4], t1v[4], t2v[4], t3v[4], t4v[4], t5v[4], t6v[4], t7v[4];
    tap4<D0>(p, t0v);
    tap4<D1>(p, t1v);
    tap4<D2>(p, t2v);
    tap4<D3>(p, t3v);
    tap4<D4>(p, t4v);
    tap4<D5>(p, t5v);
    tap4<D6>(p, t6v);
    tap4<D7>(p, t7v);

    float4 o;
#pragma unroll
    for (int k = 0; k < 4; ++k) {
        float wet = 0.f;
        wet = fmaf(c[0], t0v[k], wet);
        wet = fmaf(c[1], t1v[k], wet);
        wet = fmaf(c[2], t2v[k], wet);
        wet = fmaf(c[3], t3v[k], wet);
        wet = fmaf(c[4], t4v[k], wet);
        wet = fmaf(c[5], t5v[k], wet);
        wet = fmaf(c[6], t6v[k], wet);
        wet = fmaf(c[7], t7v[k], wet);
        (&o.x)[k] = fmaf(0.5f, wet, 0.5f * (&dry.x)[k]);
    }
    return o;
}

// Stage [blk*CHUNK - HALO, blk*CHUNK + CHUNK) into LDS; zeros before t=0.
__device__ __forceinline__ void stage(const float* __restrict__ x, float* smem,
                                      int blk, int tid) {
    const long gs = (long)blk * CHUNK - HALO;
    for (int v4 = tid; v4 < LDSF / 4; v4 += 256) {
        long ga = gs + (long)v4 * 4;
        float4 val = make_float4(0.f, 0.f, 0.f, 0.f);
        if (ga >= 0) val = *(const float4*)(x + ga);
        *(float4*)(smem + v4 * 4) = val;
    }
}

__device__ __forceinline__ void load_coeffs(const float* __restrict__ g,
                                            const float* __restrict__ Q,
                                            float* csh, int tid) {
    if (tid < 8) {
        float s = 0.f;
#pragma unroll
        for (int j = 0; j < 8; ++j) s += Q[j * 8 + tid];
        csh[tid] = s * g[tid];
    }
}

// Pass A: FIR once; store un-normalized output (regular stores -> L2);
// block max -> slots[blk].
__global__ __launch_bounds__(256) void fdn_wet(
    const float* __restrict__ x, const float* __restrict__ g,
    const float* __restrict__ Q, float* __restrict__ slots,
    float* __restrict__ out) {
    __shared__ __align__(16) float smem[LDSF];
    __shared__ float csh[8];
    __shared__ float wmax[4];

    const int tid = threadIdx.x;
    const int blk = swz(blockIdx.x);

    load_coeffs(g, Q, csh, tid);
    stage(x, smem, blk, tid);
    __syncthreads();

    float c[8];
#pragma unroll
    for (int n = 0; n < 8; ++n) c[n] = csh[n];

    const int base = blk * CHUNK;
    float m = 0.f;
#pragma unroll
    for (int i = 0; i < CHUNK / 1024; ++i) {
        const int j = i * 1024 + tid * 4;
        float4 o = quad_fir(smem + HALO + j, c);
        m = fmaxf(m, fmaxf(fmaxf(fabsf(o.x), fabsf(o.y)),
                           fmaxf(fabsf(o.z), fabsf(o.w))));
        *(float4*)(out + base + j) = o;   // regular store: keep in L2 for pass B
    }

#pragma unroll
    for (int off = 32; off > 0; off >>= 1) m = fmaxf(m, __shfl_down(m, off, 64));
    if ((tid & 63) == 0) wmax[tid >> 6] = m;
    __syncthreads();
    if (tid == 0)
        slots[blk] = fmaxf(fmaxf(wmax[0], wmax[1]), fmaxf(wmax[2], wmax[3]));
}

// Pass B: reduce slots -> inv, scale out in place (nontemporal final write).
__global__ __launch_bounds__(256) void fdn_scale(
    const float* __restrict__ slots, float* __restrict__ out) {
    __shared__ float wmax[4];

    const int tid = threadIdx.x;
    const int blk = swz(blockIdx.x);  // same phys->XCD mapping as pass A writer

    // each thread covers 8 of the 2048 slots (two float4 loads)
    float4 s0 = *(const float4*)(slots + tid * 8);
    float4 s1 = *(const float4*)(slots + tid * 8 + 4);
    float m = fmaxf(fmaxf(fmaxf(s0.x, s0.y), fmaxf(s0.z, s0.w)),
                    fmaxf(fmaxf(s1.x, s1.y), fmaxf(s1.z, s1.w)));
#pragma unroll
    for (int off = 32; off > 0; off >>= 1) m = fmaxf(m, __shfl_down(m, off, 64));
    if ((tid & 63) == 0) wmax[tid >> 6] = m;
    __syncthreads();
    const float inv = 1.0f / fmaxf(fmaxf(wmax[0], wmax[1]),
                                   fmaxf(wmax[2], wmax[3]));

    const int base = blk * CHUNK;
#pragma unroll
    for (int i = 0; i < CHUNK / 1024; ++i) {
        const int j = i * 1024 + tid * 4;
        float4 v = *(const float4*)(out + base + j);
        floatx4 ov;
        ov.x = v.x * inv; ov.y = v.y * inv;
        ov.z = v.z * inv; ov.w = v.w * inv;
        __builtin_nontemporal_store(ov, (floatx4*)(out + base + j));
    }
}

extern "C" void kernel_launch(void* const* d_in, const int* in_sizes, int n_in,
                              void* d_out, int out_size, void* d_ws, size_t ws_size,
                              hipStream_t stream) {
    const float* x = (const float*)d_in[0];       // input_sig [1, T]
    const float* g = (const float*)d_in[1];       // feedback_gain [8]
    const float* Q = (const float*)d_in[2];       // orthogonal_matrix [8,8]
    float* out = (float*)d_out;
    float* slots = (float*)d_ws;                  // 2048 per-block maxes
                                                  // (written unconditionally by
                                                  //  pass A before pass B reads)

    fdn_wet  <<<dim3(NBLK), dim3(256), 0, stream>>>(x, g, Q, slots, out);
    fdn_scale<<<dim3(NBLK), dim3(256), 0, stream>>>(slots, out);
}